// Round 7
// baseline (582.890 us; speedup 1.0000x reference)
//
#include <hip/hip_runtime.h>
#include <hip/hip_bf16.h>

// Qriaffine: out[n,i,j] = sum_{a,b,c,d} l1[n,i,a] W[a,b,c,d] l2[n,j,b] h1[n,i,c] h2[n,j,d]
// Plan:
//   P[(n,i)][(a*65+c)] = l1[a]*h1[c]        (8192 x 4225, bf16, pad K->4288)
//   Wt2[(b*65+d)][(a*65+c)] = W[a,b,c,d]    (4225 x 4225, bf16, pad -> 4352 x 4288)
//   Q = P @ Wt2 (NT gemm)                   (8192 x 4352, bf16)
//   R[(n,j)][(b*65+d)] = l2[b]*h2[d]        (8192 x 4352, bf16, built AFTER gemm1)
//   out_n = Q_n @ R_n^T (NT gemm, f32 out)  (8 x 1024 x 1024)
//
// R9: gemm1 locked at the m97-structure ceiling (882 TF; restructures R4/R5/
// R6 all regressed; fp8 infeasible by error arithmetic: ~7%/elem -> |err|~10
// vs threshold 4). Tail work only:
//   1. gemm2 SWZ=2 extended with intra-XCD 2x2 tile grouping: live set
//      2A+2B ~ 4.4MB ~ L2 -> B-panel re-reads 8x(L3) -> 4x(L2-ish).
//   2. zero_pad fused into build_wt2 (grid (65,66); y==65 zeroes pads).
//   3. build_p 8 rows/block (grid 1024).

typedef __attribute__((ext_vector_type(8))) short short8;     // 8 bf16 = 4 VGPRs
typedef __attribute__((ext_vector_type(16))) float floatx16;  // MFMA 32x32 acc

#define KP 4288   // padded (a,c) dim: 67*64
#define DP 4352   // padded (b,d) dim: 68*64 = 34*128
#define NROW 8192 // n*L

__device__ __forceinline__ void async_ld16(const void* g, void* l) {
  __builtin_amdgcn_global_load_lds(
      (const __attribute__((address_space(1))) unsigned int*)g,
      (__attribute__((address_space(3))) unsigned int*)l, 16, 0, 0);
}

// ---------------- W[a,b,c,d] -> Wt2[(b*65+d)][(a*65+c)] (bf16) ----------------
// grid (65, 66): y<65 -> transpose block (a=x, b=y); y==65 -> pad zeroing
// (rows 4225..4351 full width; rows 0..4224 cols 4225..4287). Disjoint writes.
__global__ void build_wt2(const float* __restrict__ W, __hip_bfloat16* __restrict__ Wt2) {
  if (blockIdx.y == 65) {
    const int ROWPAD = 127 * KP;    // 544,576
    const int COLPAD = 4225 * 63;   // 266,175
    const int total = ROWPAD + COLPAD;
    const __hip_bfloat16 z = __float2bfloat16(0.f);
    for (int id = blockIdx.x * 256 + threadIdx.x; id < total; id += 65 * 256) {
      if (id < ROWPAD) {
        int row = 4225 + id / KP, col = id % KP;
        Wt2[(size_t)row * KP + col] = z;
      } else {
        int j = id - ROWPAD;
        int row = j / 63, col = 4225 + j % 63;
        Wt2[(size_t)row * KP + col] = z;
      }
    }
    return;
  }
  __shared__ __hip_bfloat16 tile[65 * 66];
  const int a = blockIdx.x, b = blockIdx.y;
  const float* src = W + (size_t)(a * 65 + b) * 4225;  // contiguous (c,d) plane
  for (int idx = threadIdx.x; idx < 4225; idx += 256) {
    int c = idx / 65, d = idx - c * 65;
    tile[d * 66 + c] = __float2bfloat16(src[idx]);
  }
  __syncthreads();
  for (int idx = threadIdx.x; idx < 4225; idx += 256) {
    int d = idx / 65, c = idx - d * 65;
    Wt2[(size_t)(b * 65 + d) * KP + a * 65 + c] = tile[d * 66 + c];
  }
}

// ---------------- P/R builder: P[row][x*65+y] = layer_row[x] * h_row[y] ----------------
// 8 rows per block (grid = NROW/8) to amortize block setup.
__global__ void build_p(const float* __restrict__ layer, const float* __restrict__ h,
                        __hip_bfloat16* __restrict__ P, int width) {
  const int row0 = blockIdx.x * 8;
  __shared__ float lv[8][65], hv[8][65];
  for (int i = threadIdx.x; i < 520; i += 256) {
    int rr = i / 65, x = i - rr * 65;
    lv[rr][x] = (x < 64) ? layer[(size_t)(row0 + rr) * 64 + x] : 1.0f;
    hv[rr][x] = h[(size_t)(row0 + rr) * 65 + x];
  }
  __syncthreads();
#pragma unroll
  for (int rr = 0; rr < 8; ++rr) {
    const size_t rowbase = (size_t)(row0 + rr) * width;
    for (int base = threadIdx.x * 8; base < width; base += 256 * 8) {
      alignas(16) __hip_bfloat16 tmp[8];
#pragma unroll
      for (int j = 0; j < 8; ++j) {
        int idx = base + j;
        float v = 0.f;
        if (idx < 4225) {
          int x = idx / 65, y = idx - x * 65;
          v = lv[rr][x] * hv[rr][y];
        }
        tmp[j] = __float2bfloat16(v);
      }
      *(float4*)(P + rowbase + base) = *(const float4*)tmp;
    }
  }
}

// ---------------- NT GEMM (proven R3 kernel) ----------------
// A: M x K (lda), B: N x K (ldb), row-major bf16, K % 64 == 0.
// 128x128 block tile, 4 waves each 64x64 = 2x2 tiles of 32x32, BK=64,
// mfma_f32_32x32x16_bf16. Staging via global_load_lds x16, XOR-swizzled LDS.
// SWZ=1 (gemm1; grid exactly (34,64,1)): locality remap -- XCD k
// (linear-dispatch mod 8) owns M-rows [8k,8k+8); x swept in groups of 9.
// Bijective (verified R7: FETCH 643->272MB).
// SWZ=2 (gemm2; grid exactly (8,8,8)): batch-per-XCD remap (XCD k owns
// batch z=k) + intra-XCD 2x2 tile grouping (live set 2 A-panels + 2
// B-panels ~ 4.4MB ~ L2, halves panel re-reads vs bx-fastest order).
// orig = bx+8*by+64*bz: z'=orig&7; r=orig>>3 in [0,64); g=r>>2; q=r&3;
// bx'=(g&3)*2+(q&1); by'=(g>>2)*2+(q>>1). Bijective.
template <int STORE_BF16, int SWZ>
__global__ __launch_bounds__(256) void gemm_nt(
    const __hip_bfloat16* __restrict__ A, const __hip_bfloat16* __restrict__ B,
    void* __restrict__ Cv, int K, int lda, int ldb, int ldc,
    long sA, long sB, long sC) {
  __shared__ alignas(16) __hip_bfloat16 As[128 * 64];
  __shared__ alignas(16) __hip_bfloat16 Bs[128 * 64];
  int bx = blockIdx.x, by = blockIdx.y, z = blockIdx.z;
  if (SWZ == 1) {
    int orig = blockIdx.x + 34 * blockIdx.y;  // grid (34,64) -> 0..2175
    int xcd = orig & 7;
    int idx = orig >> 3;                      // 0..271
    int xg = (idx < 216) ? (idx / 72) : 3;
    int r = idx - xg * 72;
    bx = xg * 9 + (r >> 3);
    by = (xcd << 3) + (r & 7);
  } else if (SWZ == 2) {
    int orig = blockIdx.x + 8 * blockIdx.y + 64 * blockIdx.z;  // 0..511
    z = orig & 7;
    int r = orig >> 3;  // 0..63
    int g = r >> 2, q = r & 3;
    bx = (g & 3) * 2 + (q & 1);
    by = (g >> 2) * 2 + (q >> 1);
  }
  A += (long)z * sA;
  B += (long)z * sB;
  const int bm = by * 128;
  const int bn = bx * 128;
  const int t = threadIdx.x;
  const int lane = t & 63;
  const int wave = t >> 6;
  const int l31 = lane & 31;
  const int lhi = lane >> 5;
  const int wm = (wave >> 1) * 64;
  const int wn = (wave & 1) * 64;

  const __hip_bfloat16* gA[4];
  const __hip_bfloat16* gB[4];
  __hip_bfloat16* lA[4];
  __hip_bfloat16* lB[4];
#pragma unroll
  for (int r = 0; r < 4; ++r) {
    int L = r * 256 + t;
    int row = L >> 3, sl = L & 7;
    int sg = sl ^ (row & 7);
    gA[r] = A + (size_t)(bm + row) * lda + sg * 8;
    gB[r] = B + (size_t)(bn + row) * ldb + sg * 8;
    lA[r] = As + (size_t)(r * 256 + wave * 64) * 8;
    lB[r] = Bs + (size_t)(r * 256 + wave * 64) * 8;
  }

  const int x7 = l31 & 7;
  const int rA0 = (wm + l31) * 64, rA1 = (wm + 32 + l31) * 64;
  const int rB0 = (wn + l31) * 64, rB1 = (wn + 32 + l31) * 64;

  floatx16 acc[2][2] = {};

  for (int k0 = 0; k0 < K; k0 += 64) {
    __syncthreads();
#pragma unroll
    for (int r = 0; r < 4; ++r) {
      async_ld16(gA[r] + k0, lA[r]);
      async_ld16(gB[r] + k0, lB[r]);
    }
    __syncthreads();

#pragma unroll
    for (int ks = 0; ks < 4; ++ks) {
      const int pc = ((ks * 2 + lhi) ^ x7) * 8;
      short8 a0 = *(const short8*)(&As[rA0 + pc]);
      short8 a1 = *(const short8*)(&As[rA1 + pc]);
      short8 b0 = *(const short8*)(&Bs[rB0 + pc]);
      short8 b1 = *(const short8*)(&Bs[rB1 + pc]);
      acc[0][0] = __builtin_amdgcn_mfma_f32_32x32x16_bf16(a0, b0, acc[0][0], 0, 0, 0);
      acc[0][1] = __builtin_amdgcn_mfma_f32_32x32x16_bf16(a0, b1, acc[0][1], 0, 0, 0);
      acc[1][0] = __builtin_amdgcn_mfma_f32_32x32x16_bf16(a1, b0, acc[1][0], 0, 0, 0);
      acc[1][1] = __builtin_amdgcn_mfma_f32_32x32x16_bf16(a1, b1, acc[1][1], 0, 0, 0);
    }
  }

  // C/D layout (verified m74/m101): col = lane&31,
  // row = (reg&3) + 8*(reg>>2) + 4*(lane>>5)
  if (STORE_BF16) {
    __hip_bfloat16* C = (__hip_bfloat16*)Cv + (long)z * sC;
#pragma unroll
    for (int mt = 0; mt < 2; ++mt)
#pragma unroll
      for (int nt = 0; nt < 2; ++nt)
#pragma unroll
        for (int reg = 0; reg < 16; ++reg) {
          int row = bm + wm + mt * 32 + (reg & 3) + 8 * (reg >> 2) + 4 * lhi;
          int col = bn + wn + nt * 32 + l31;
          C[(size_t)row * ldc + col] = __float2bfloat16(acc[mt][nt][reg]);
        }
  } else {
    float* C = (float*)Cv + (long)z * sC;
#pragma unroll
    for (int mt = 0; mt < 2; ++mt)
#pragma unroll
      for (int nt = 0; nt < 2; ++nt)
#pragma unroll
        for (int reg = 0; reg < 16; ++reg) {
          int row = bm + wm + mt * 32 + (reg & 3) + 8 * (reg >> 2) + 4 * lhi;
          int col = bn + wn + nt * 32 + l31;
          C[(size_t)row * ldc + col] = acc[mt][nt][reg];
        }
  }
}

extern "C" void kernel_launch(void* const* d_in, const int* in_sizes, int n_in,
                              void* d_out, int out_size, void* d_ws, size_t ws_size,
                              hipStream_t stream) {
  const float* layer1 = (const float*)d_in[0];
  const float* layer2 = (const float*)d_in[1];
  const float* h1 = (const float*)d_in[3];
  const float* h2 = (const float*)d_in[4];
  const float* W = (const float*)d_in[6];
  float* out = (float*)d_out;

  // workspace layout (bytes), total high-water 178,880,512:
  //   [0 .. 70,254,592)            P  (8192*4288*2)   -- later reused for R
  //   [70,254,592 .. 107,577,344)  Wt2 (4352*4288*2)
  //   [107,577,344 .. 178,880,512) Q  (8192*4352*2)
  char* ws = (char*)d_ws;
  __hip_bfloat16* P = (__hip_bfloat16*)(ws);
  __hip_bfloat16* Wt2 = (__hip_bfloat16*)(ws + 70254592ULL);
  __hip_bfloat16* Q = (__hip_bfloat16*)(ws + 107577344ULL);
  __hip_bfloat16* R = (__hip_bfloat16*)(ws);  // reuses P/Wt2 region

  // 1) transpose+cast W; y==65 blocks zero the pad regions (fused)
  build_wt2<<<dim3(65, 66), 256, 0, stream>>>(W, Wt2);
  // 2) P (8 rows per block)
  build_p<<<NROW / 8, 256, 0, stream>>>(layer1, h1, P, KP);
  // 3) Q = P @ Wt2 (NT): M=8192, N=4352, K=4288 — R3 kernel + locality remap
  gemm_nt<1, 1><<<dim3(DP / 128, NROW / 128, 1), 256, 0, stream>>>(
      P, Wt2, Q, KP, KP, KP, DP, 0, 0, 0);
  // 4) R (over the now-dead P/Wt2 region)
  build_p<<<NROW / 8, 256, 0, stream>>>(layer2, h2, R, DP);
  // 5) out_n = Q_n @ R_n^T: M=N=1024, K=4288 (cols 4225..4287 are zeros),
  //    batched over n=8, batch-per-XCD + 2x2 grouping remap
  gemm_nt<0, 2><<<dim3(1024 / 128, 1024 / 128, 8), 256, 0, stream>>>(
      Q, R, out, 4288, DP, DP, 1024, 1024L * DP, 1024L * DP, 1024L * 1024);
}